// Round 7
// baseline (195.046 us; speedup 1.0000x reference)
//
#include <hip/hip_runtime.h>

#define BB 4
#define PP 10
#define NN 400000
#define HH 480
#define WW 640
constexpr int HW    = HH * WW;        // 307200
constexpr int NXB   = HW / 256;       // 1200 (focus blocks per image)
constexpr int NXB4  = HW / 1024;      // 300 (flow tiles per plane, 4 px/thread)
constexpr int NTILE = NXB4 * BB * PP; // 12000 flow tiles
constexpr int NPB   = 2048;           // persistent blocks (256 CU x 8)
constexpr int CHUNK = NTILE / 8;      // 1500 tiles per XCD
constexpr int EVB   = (BB * NN + NPB - 1) / NPB;   // 782 events per block

// quad images: 4 parity images, each [BB][2][240][320] u64 quads
constexpr int QW = WW / 2, QH = HH / 2, QN = QW * QH;
constexpr size_t IMG_QUADS = (size_t)4 * BB * 2 * QN;   // 19.66 MB

constexpr float SCALE     = 1024.0f;
constexpr float INV_SCALE = 1.0f / 1024.0f;

// ---- partial-sum layout (floats) ----
constexpr int PF_V = 0;                         // [BB][NXB]
constexpr int PF_N = PF_V + BB * NXB;
constexpr int PT_D = PF_N + BB * NXB;           // [BB*(PP-1)][NXB4]
constexpr int PT_M = PT_D + BB * (PP-1) * NXB4;
constexpr int PS   = PT_M + BB * (PP-1) * NXB4; // [BB*PP][NXB4]
constexpr int NPART = PS + BB * PP * NXB4;

// ---------- helpers ----------

__device__ __forceinline__ float fsq(float a) { return __builtin_amdgcn_sqrtf(a); }
__device__ __forceinline__ float charb(float a) { return fsq(fmaf(a, a, 1e-6f)); }

// one-barrier-pair triple block reduction; results valid on thread 0
__device__ __forceinline__ void blockSum3(float a, float b, float c, float* sm, int t,
                                          float& ra, float& rb, float& rc) {
    #pragma unroll
    for (int off = 32; off > 0; off >>= 1) {
        a += __shfl_down(a, off, 64);
        b += __shfl_down(b, off, 64);
        c += __shfl_down(c, off, 64);
    }
    int lane = t & 63, wid = t >> 6;
    if (lane == 0) { sm[wid] = a; sm[4 + wid] = b; sm[8 + wid] = c; }
    __syncthreads();
    if (t == 0) {
        ra = sm[0] + sm[1] + sm[2] + sm[3];
        rb = sm[4] + sm[5] + sm[6] + sm[7];
        rc = sm[8] + sm[9] + sm[10] + sm[11];
    }
    __syncthreads();
}

__device__ __forceinline__ float blockSum256(float v, float* smem) {
    #pragma unroll
    for (int off = 32; off > 0; off >>= 1)
        v += __shfl_down(v, off, 64);
    int lane = threadIdx.x & 63;
    int wid  = threadIdx.x >> 6;
    if (lane == 0) smem[wid] = v;
    __syncthreads();
    float r = 0.f;
    if (threadIdx.x == 0) r = smem[0] + smem[1] + smem[2] + smem[3];
    __syncthreads();
    return r;
}

__device__ __forceinline__ void scatter_one(int e,
                                            const float2* __restrict__ we,
                                            const float* __restrict__ pol,
                                            const float* __restrict__ tsl,
                                            unsigned long long* __restrict__ img) {
    int b = e / NN;
    int m = e - b * NN;
    float2 c = we[e];
    float y = c.x, x = c.y;
    float pm0 = pol[((size_t)b * 4 * NN + m) * 2];
    float ts  = tsl[(size_t)b * 4 * NN + m];
    float nts = 1.0f - fabsf(1.0f - ts);
    float tyf = fminf(fmaxf(floorf(y), 0.f), (float)(HH - 2));
    float lxf = fminf(fmaxf(floorf(x), 0.f), (float)(WW - 2));
    float fy_ = y - tyf, fx_ = x - lxf;
    float gy = 1.f - fy_, gx = 1.f - fx_;
    float s = nts * SCALE;
    unsigned long long wTL = (unsigned int)(gy * gx * s + 0.5f);
    unsigned long long wTR = (unsigned int)(gy * fx_ * s + 0.5f);
    unsigned long long wBL = (unsigned int)(fy_ * gx * s + 0.5f);
    unsigned long long wBR = (unsigned int)(fy_ * fx_ * s + 0.5f);
    unsigned long long val = wTL | (wTR << 16) | (wBL << 32) | (wBR << 48);
    int ty = (int)tyf, lx = (int)lxf;
    int pi = ((ty & 1) << 1) | (lx & 1);
    int pl = (pm0 > 0.5f) ? 0 : 1;
    size_t wi = ((size_t)((pi * BB + b) * 2 + pl)) * QN + (ty >> 1) * QW + (lx >> 1);
    atomicAdd(&img[wi], val);
}

// ---------- 1. persistent fused scatter + spatial + temporal ----------

__global__ __launch_bounds__(256)
void fused_kernel(const float2* __restrict__ we,
                  const float* __restrict__ pol,
                  const float* __restrict__ tsl,
                  const float* __restrict__ FX, const float* __restrict__ FY,
                  unsigned long long* __restrict__ img,
                  float* __restrict__ part) {
    __shared__ float sm[12];
    int w = blockIdx.x;
    int t = threadIdx.x;
    int ebase = w * EVB;
    int ecnt  = BB * NN - ebase;              // may exceed EVB or be <=0
    if (ecnt > EVB) ecnt = EVB;
    int xcd = w & 7, slot = w >> 3;

    int it = 0;
    for (int s = slot; s < CHUNK; s += 256, ++it) {
        // --- interleaved scatter sub-chunk (256 events/block/iteration) ---
        int k = it * 256 + t;
        if (k < ecnt) scatter_one(ebase + k, we, pol, tsl, img);

        // --- flow tile ---
        int l  = xcd * CHUNK + s;
        int bp = l / NXB4;
        int xb = l - bp * NXB4;
        int b2 = bp / PP;
        int j  = bp - b2 * PP;
        int p0 = xb * 1024 + t * 4;
        int y  = p0 / WW;
        int x0 = p0 - y * WW;                 // multiple of 4 (640%4==0)
        const float* fx = FX + (size_t)bp * HW;
        const float* fy = FY + (size_t)bp * HW;
        float4 vx = *(const float4*)(fx + p0);
        float4 vy = *(const float4*)(fy + p0);
        bool yin  = (y + 1 < HH);
        bool xend = (x0 == WW - 4);
        float4 bx4 = make_float4(0.f, 0.f, 0.f, 0.f), by4 = bx4;
        float vxr = 0.f, vyr = 0.f, bxr = 0.f, byr = 0.f;
        if (yin) {
            bx4 = *(const float4*)(fx + p0 + WW);
            by4 = *(const float4*)(fy + p0 + WW);
        }
        if (!xend) { vxr = fx[p0 + 4]; vyr = fy[p0 + 4]; }
        if (yin && !xend) { bxr = fx[p0 + WW + 4]; byr = fy[p0 + WW + 4]; }

        constexpr float cdx = 1.0f / ((float)HH * (WW - 1) * 4.0f * PP);
        constexpr float cdy = 1.0f / ((float)(HH - 1) * WW * 4.0f * PP);
        constexpr float cdd = 1.0f / ((float)(HH - 1) * (WW - 1) * 4.0f * PP);

        float acc = 0.f;
        acc += (charb(vx.x - vx.y) + charb(vy.x - vy.y)) * cdx;
        acc += (charb(vx.y - vx.z) + charb(vy.y - vy.z)) * cdx;
        acc += (charb(vx.z - vx.w) + charb(vy.z - vy.w)) * cdx;
        if (!xend) acc += (charb(vx.w - vxr) + charb(vy.w - vyr)) * cdx;
        if (yin) {
            acc += (charb(vx.x - bx4.x) + charb(vy.x - by4.x)) * cdy;
            acc += (charb(vx.y - bx4.y) + charb(vy.y - by4.y)) * cdy;
            acc += (charb(vx.z - bx4.z) + charb(vy.z - by4.z)) * cdy;
            acc += (charb(vx.w - bx4.w) + charb(vy.w - by4.w)) * cdy;
            acc += (charb(vx.x - bx4.y) + charb(vy.x - by4.y)) * cdd;
            acc += (charb(vx.y - bx4.z) + charb(vy.y - by4.z)) * cdd;
            acc += (charb(vx.z - bx4.w) + charb(vy.z - by4.w)) * cdd;
            acc += (charb(bx4.x - vx.y) + charb(by4.x - vy.y)) * cdd;
            acc += (charb(bx4.y - vx.z) + charb(by4.y - vy.z)) * cdd;
            acc += (charb(bx4.z - vx.w) + charb(by4.z - vy.w)) * cdd;
            if (!xend) {
                acc += (charb(vx.w - bxr) + charb(vy.w - byr)) * cdd;
                acc += (charb(bx4.w - vxr) + charb(by4.w - vyr)) * cdd;
            }
        }

        float td = 0.f, tm = 0.f;
        if (j < PP - 1) {
            const float* gx1 = fx + HW;
            const float* gy1 = fy + HW;
            float ax[4] = {vx.x, vx.y, vx.z, vx.w};
            float ay[4] = {vy.x, vy.y, vy.z, vy.w};
            #pragma unroll
            for (int i = 0; i < 4; ++i) {
                float ly  = (float)y + ay[i];
                float lx2 = (float)(x0 + i) + ax[i];
                bool m = (ly >= 0.f) && (ly <= (float)(HH - 1)) &&
                         (lx2 >= 0.f) && (lx2 <= (float)(WW - 1));
                if (m) {
                    tm += 1.f;
                    float tyf = fminf(fmaxf(floorf(ly),  0.f), (float)(HH - 2));
                    float txf = fminf(fmaxf(floorf(lx2), 0.f), (float)(WW - 2));
                    float fyy = ly - tyf, fxx = lx2 - txf;
                    float gyy = 1.f - fyy, gxx = 1.f - fxx;
                    int pix = (int)tyf * WW + (int)txf;
                    float sx = gyy * (gxx * gx1[pix]      + fxx * gx1[pix + 1]) +
                               fyy * (gxx * gx1[pix + WW] + fxx * gx1[pix + WW + 1]);
                    float sy = gyy * (gxx * gy1[pix]      + fxx * gy1[pix + 1]) +
                               fyy * (gxx * gy1[pix + WW] + fxx * gy1[pix + WW + 1]);
                    float dy_ = ay[i] - sy;
                    float dx_ = ax[i] - sx;
                    td += fsq(fmaf(dy_, dy_, 1e-9f)) + fsq(fmaf(dx_, dx_, 1e-9f));
                }
            }
        }

        float racc, rsd, rsM;
        blockSum3(acc, td, tm, sm, t, racc, rsd, rsM);
        if (t == 0) {
            part[PS + bp * NXB4 + xb] = racc;
            if (j < PP - 1) {
                int bj = b2 * (PP - 1) + j;
                part[PT_D + bj * NXB4 + xb] = rsd;
                part[PT_M + bj * NXB4 + xb] = rsM;
            }
        }
    }
}

// ---------- 2. focus reduction -> partials ----------

__global__ __launch_bounds__(256)
void focus_kernel(const unsigned long long* __restrict__ img,
                  float* __restrict__ part) {
    __shared__ float sm[8];
    int b = blockIdx.y;
    int p = blockIdx.x * 256 + threadIdx.x;
    int y = p / WW;
    int x = p - y * WW;
    unsigned int sp = 0, sn = 0;
    #pragma unroll
    for (int dy = 0; dy < 2; ++dy) {
        #pragma unroll
        for (int dx = 0; dx < 2; ++dx) {
            int ty = y - dy, lx = x - dx;
            if (ty < 0 || lx < 0 || ty > HH - 2 || lx > WW - 2) continue;
            int pi = ((ty & 1) << 1) | (lx & 1);
            size_t base = ((size_t)(pi * BB + b) * 2) * QN + (ty >> 1) * QW + (lx >> 1);
            int sh = 16 * ((dy << 1) | dx);
            sp += (unsigned int)((img[base]      >> sh) & 0xFFFFull);
            sn += (unsigned int)((img[base + QN] >> sh) & 0xFFFFull);
        }
    }
    float tp = (float)sp * INV_SCALE;
    float tn = (float)sn * INV_SCALE;
    float v  = tp * tp + tn * tn;
    float nz = ((sp | sn) != 0u) ? 1.f : 0.f;
    float sv  = blockSum256(v, sm);
    float snz = blockSum256(nz, sm + 4);
    if (threadIdx.x == 0) {
        part[PF_V + b * NXB + blockIdx.x] = sv;
        part[PF_N + b * NXB + blockIdx.x] = snz;
    }
}

// ---------- 3. segment reduce ----------

__global__ __launch_bounds__(256)
void reduce_kernel(const float* __restrict__ part, float* __restrict__ seg) {
    __shared__ float sm[4];
    int s = blockIdx.x;                  // 0..80
    int base, len;
    if (s < 4)       { base = PF_V + s * NXB;         len = NXB; }
    else if (s < 8)  { base = PF_N + (s - 4) * NXB;   len = NXB; }
    else if (s < 44) { base = PT_D + (s - 8) * NXB4;  len = NXB4; }
    else if (s < 80) { base = PT_M + (s - 44) * NXB4; len = NXB4; }
    else             { base = PS;                     len = BB * PP * NXB4; }
    float v = 0.f;
    for (int i = threadIdx.x; i < len; i += 256) v += part[base + i];
    float r = blockSum256(v, sm);
    if (threadIdx.x == 0) seg[s] = r;
}

// ---------- 4. final combine ----------

__global__ void final_kernel(const float* __restrict__ seg, float* __restrict__ out) {
    if (threadIdx.x == 0 && blockIdx.x == 0) {
        float focus = 0.f;
        #pragma unroll
        for (int b = 0; b < BB; ++b)
            focus += seg[b] / (seg[BB + b] + 1e-9f);
        float temporal = 0.f;
        #pragma unroll
        for (int k = 0; k < BB * (PP - 1); ++k)
            temporal += seg[8 + k] / (seg[44 + k] + 1e-9f);
        temporal *= 1.0f / (float)(PP - 1);
        out[0] = focus + temporal + seg[80];
    }
}

// ---------- launch ----------

extern "C" void kernel_launch(void* const* d_in, const int* in_sizes, int n_in,
                              void* d_out, int out_size, void* d_ws, size_t ws_size,
                              hipStream_t stream) {
    const float2* we  = (const float2*)d_in[0];  // [B,N,2]
    const float*  pol = (const float*)d_in[1];   // [B,4N,2]
    const float*  tsl = (const float*)d_in[2];   // [B,4N,1]
    const float*  FX  = (const float*)d_in[3];   // [B,P,H,W]
    const float*  FY  = (const float*)d_in[4];   // [B,P,H,W]
    float*              seg  = (float*)d_ws;
    unsigned long long* img  = (unsigned long long*)(seg + 256);   // 8B-aligned
    float*              part = (float*)(img + IMG_QUADS);

    hipMemsetAsync(img, 0, IMG_QUADS * sizeof(unsigned long long), stream);

    fused_kernel<<<NPB, 256, 0, stream>>>(we, pol, tsl, FX, FY, img, part);
    focus_kernel<<<dim3(NXB, BB), 256, 0, stream>>>(img, part);
    reduce_kernel<<<81, 256, 0, stream>>>(part, seg);
    final_kernel<<<1, 64, 0, stream>>>(seg, (float*)d_out);
}